// Round 15
// baseline (22406.927 us; speedup 1.0000x reference)
//
#include <hip/hip_runtime.h>
#include <math.h>

#define BB 32
#define TT 2048
#define FF 16
#define CC 17
#define HH 64

typedef float v2f __attribute__((ext_vector_type(2)));
typedef float v4f __attribute__((ext_vector_type(4)));
typedef unsigned v4u __attribute__((ext_vector_type(4)));
typedef _Float16 h2 __attribute__((ext_vector_type(2)));

__device__ __forceinline__ float rl(float v, int lane) {
    return __int_as_float(__builtin_amdgcn_readlane(__float_as_int(v), lane));
}
__device__ __forceinline__ unsigned rlu(unsigned v, int lane) {
    return (unsigned)__builtin_amdgcn_readlane((int)v, lane);
}
__device__ __forceinline__ float uf(float v) {
    return __int_as_float(__builtin_amdgcn_readfirstlane(__float_as_int(v)));
}
__device__ __forceinline__ float ftanh(float x) {
    float e = __builtin_amdgcn_exp2f(x * 2.88539008177792681472f); // exp(2x)
    return 1.0f - 2.0f * __builtin_amdgcn_rcpf(e + 1.0f);
}
__device__ __forceinline__ float fdot2u(unsigned a, unsigned b, float c) {
    return __builtin_amdgcn_fdot2(__builtin_bit_cast(h2, a),
                                  __builtin_bit_cast(h2, b), c, false);
}
// pack (a,b) to f16x2, scaled by 2^8 (weights); RN; init-time only
__device__ __forceinline__ unsigned packw(float a, float b) {
    h2 p; p.x = (_Float16)(a * 256.0f); p.y = (_Float16)(b * 256.0f);
    return __builtin_bit_cast(unsigned, p);
}
// LDS-only barrier: no vmcnt(0) drain.
__device__ __forceinline__ void bar_lds() {
    asm volatile("s_waitcnt lgkmcnt(0)\n\ts_barrier" ::: "memory");
}
#define PIN(v) asm volatile("" : "+v"(v))

// R14 pipeline DUALIZED AT THE WAVE LEVEL: 1024 threads = two independent
// 8-wave halves, each running the proven R14 structure on its OWN batch
// element with its OWN LDS buffers. Per-wave register state is UNCHANGED
// (R5/R10 died doubling per-wave state -> spills; this doubles waves instead).
// 4 waves/SIMD: during every LDS-latency / barrier-wake window (the ~45% of
// per-G time R8-R14 couldn't remove), the SIMD now has another element's
// waves to issue from. Barriers sync both halves, but the halves run
// identical instruction streams and arrive together.
__attribute__((amdgpu_waves_per_eu(4, 4)))
__launch_bounds__(1024)
__global__ void ncde_main(const float* __restrict__ x,
                          const float* __restrict__ wi1, const float* __restrict__ bi1,
                          const float* __restrict__ wi2, const float* __restrict__ bi2,
                          const float* __restrict__ w_in, const float* __restrict__ b_in,
                          const float* __restrict__ w_hid, const float* __restrict__ b_hid,
                          const float* __restrict__ w_out, const float* __restrict__ b_out,
                          float* __restrict__ zT)
{
    const int bid  = blockIdx.x;
    const int tid  = threadIdx.x;
    const int ww   = tid >> 6;          // 0..15
    const int half = ww >> 3;           // 0 or 1
    const int w    = ww & 7;            // wave index within half
    const int l    = tid & 63;
    const int e    = 2 * bid + half;    // this half's batch element

    __shared__ float pht[2][4][64][12];               // per-half [layer][h-row][wave-col]
    __shared__ float pgqt[2][64][20];                 // per-half [h-row][(pg,a16) x 8 cols]
    __shared__ __align__(16) unsigned hbw[16][32];    // per-wave private packed h pairs

    const int cs = w ^ ((l >> 3) & 7);   // swizzled column (order-invariant sum)

    // ---- hidden weights: wave w owns k-slice [8w,8w+8), packed 4 u32/layer ----
    unsigned whp[4][4];
    #pragma unroll
    for (int kk = 0; kk < 4; ++kk) {
        int k = 8 * w + 2 * kk;
        whp[0][kk] = packw(w_in[k * HH + l],               w_in[(k + 1) * HH + l]);
        whp[1][kk] = packw(w_hid[(0 * HH + k) * HH + l],   w_hid[(0 * HH + k + 1) * HH + l]);
        whp[2][kk] = packw(w_hid[(1 * HH + k) * HH + l],   w_hid[(1 * HH + k + 1) * HH + l]);
        whp[3][kk] = packw(w_hid[(2 * HH + k) * HH + l],   w_hid[(2 * HH + k + 1) * HH + l]);
    }
    float bfold[4];
    bfold[0] = (w == 0) ? b_in[l] : 0.0f;
    bfold[1] = (w == 0) ? b_hid[0 * HH + l] : 0.0f;
    bfold[2] = (w == 0) ? b_hid[1 * HH + l] : 0.0f;
    bfold[3] = (w == 0) ? b_hid[2 * HH + l] : 0.0f;

    // ---- out-layer weights (cols c0,c1 per wave + c16 k-slice), packed ----
    const int c0 = 2 * w, c1 = 2 * w + 1;
    unsigned wo0p[32], wo1p[32], w16p[4];
    #pragma unroll
    for (int j = 0; j < 32; ++j) {
        wo0p[j] = packw(w_out[(2 * j) * (CC * HH) + l * CC + c0],
                        w_out[(2 * j + 1) * (CC * HH) + l * CC + c0]);
        wo1p[j] = packw(w_out[(2 * j) * (CC * HH) + l * CC + c1],
                        w_out[(2 * j + 1) * (CC * HH) + l * CC + c1]);
    }
    #pragma unroll
    for (int jj = 0; jj < 4; ++jj)
        w16p[jj] = packw(w_out[(8 * w + 2 * jj) * (CC * HH) + l * CC + 16],
                         w_out[(8 * w + 2 * jj + 1) * (CC * HH) + l * CC + 16]);
    float bo0  = b_out[l * CC + c0];
    float bo1  = b_out[l * CC + c1];
    float bo16 = (w == 0) ? b_out[l * CC + 16] : 0.0f;   // folded into per-half wave0

    #pragma unroll
    for (int j = 0; j < 32; ++j) { PIN(wo0p[j]); PIN(wo1p[j]); }
    #pragma unroll
    for (int jj = 0; jj < 4; ++jj) PIN(w16p[jj]);
    #pragma unroll
    for (int lay = 0; lay < 4; ++lay) {
        PIN(whp[lay][0]); PIN(whp[lay][1]); PIN(whp[lay][2]); PIN(whp[lay][3]);
    }
    PIN(bo0); PIN(bo1); PIN(bo16);

    // ---- z0 = relu(xa0 @ wi1 + bi1) @ wi2 + bi2 (f32, once, per half) ----
    float z;
    {
        float h0 = bi1[l];
        #pragma unroll
        for (int c = 1; c < CC; ++c)
            h0 = fmaf(x[(size_t)e * TT * FF + (c - 1)], wi1[c * HH + l], h0);
        h0 = fmaxf(h0, 0.0f);
        z = bi2[l];
        #pragma unroll
        for (int k = 0; k < 64; ++k)
            z = fmaf(rl(h0, k), wi2[k * HH + l], z);
    }
    if (w == 0) zT[(size_t)e * TT * HH + l] = z;

    // pack v*2^-8 into f16x2; every lane ends holding pair (v[2j],v[2j+1]), j=l>>1
    auto packb = [&](float v) -> unsigned {
        float hs = v * 0.00390625f;
        float pr = __shfl_xor(hs, 1);
        float a  = (l & 1) ? pr : hs;
        float bb = (l & 1) ? hs : pr;
        return __builtin_bit_cast(unsigned, __builtin_amdgcn_cvt_pkrtz(a, bb));
    };

    // ---- g(zin, xd) ----
    auto G = [&](float zin, float xd0, float xd1, float xd16) -> float {
        float cur = zin;
        #pragma unroll
        for (int L = 0; L < 4; ++L) {
            unsigned hp = packb(cur);
            float a0 = bfold[L], a1 = 0.0f;
            a0 = fdot2u(rlu(hp, 8 * w + 0), whp[L][0], a0);
            a1 = fdot2u(rlu(hp, 8 * w + 2), whp[L][1], a1);
            a0 = fdot2u(rlu(hp, 8 * w + 4), whp[L][2], a0);
            a1 = fdot2u(rlu(hp, 8 * w + 6), whp[L][3], a1);
            pht[half][L][l][cs] = a0 + a1;
            bar_lds();
            const float* row = &pht[half][L][l][0];
            v4f q0 = *reinterpret_cast<const v4f*>(row);       // cols 0..3 (any order)
            v4f q1 = *reinterpret_cast<const v4f*>(row + 4);   // cols 4..7
            float hsum = ((q0.x + q0.y) + (q0.z + q0.w)) + ((q1.x + q1.y) + (q1.z + q1.w));
            cur = fmaxf(hsum, 0.0f);
        }
        // out layer: private-LDS h broadcast (R14), no readlanes
        unsigned hp = packb(cur);
        if ((l & 1) == 0) hbw[ww][l >> 1] = hp;
        float u0a = 0.f, u0b = 0.f, u0c = 0.f, u0d = 0.f;
        float u1a = 0.f, u1b = 0.f, u1c = 0.f, u1d = 0.f;
        #pragma unroll
        for (int j = 0; j < 8; ++j) {
            v4u q = *reinterpret_cast<const v4u*>(&hbw[ww][4 * j]);
            u0a = fdot2u(q.x, wo0p[4 * j + 0], u0a);
            u0b = fdot2u(q.y, wo0p[4 * j + 1], u0b);
            u0c = fdot2u(q.z, wo0p[4 * j + 2], u0c);
            u0d = fdot2u(q.w, wo0p[4 * j + 3], u0d);
            u1a = fdot2u(q.x, wo1p[4 * j + 0], u1a);
            u1b = fdot2u(q.y, wo1p[4 * j + 1], u1b);
            u1c = fdot2u(q.z, wo1p[4 * j + 2], u1c);
            u1d = fdot2u(q.w, wo1p[4 * j + 3], u1d);
        }
        v4u qc = *reinterpret_cast<const v4u*>(&hbw[ww][4 * w]);   // c16 k-slice pairs
        float a16a = fdot2u(qc.x, w16p[0], fdot2u(qc.z, w16p[2], bo16));
        float a16b = fdot2u(qc.y, w16p[1], fdot2u(qc.w, w16p[3], 0.0f));

        float u0 = ((u0a + u0b) + (u0c + u0d)) + bo0;
        float u1 = ((u1a + u1b) + (u1c + u1d)) + bo1;
        float pg = ftanh(u0) * xd0 + ftanh(u1) * xd1;
        *reinterpret_cast<v2f*>(&pgqt[half][l][2 * cs]) = (v2f){ pg, a16a + a16b };
        bar_lds();
        const float* prow = &pgqt[half][l][0];
        v4f r0 = *reinterpret_cast<const v4f*>(prow);
        v4f r1 = *reinterpret_cast<const v4f*>(prow + 4);
        v4f r2 = *reinterpret_cast<const v4f*>(prow + 8);
        v4f r3 = *reinterpret_cast<const v4f*>(prow + 12);
        float pgs  = ((r0.x + r0.z) + (r1.x + r1.z)) + ((r2.x + r2.z) + (r3.x + r3.z));
        float a16s = ((r0.y + r0.w) + (r1.y + r1.w)) + ((r2.y + r2.w) + (r3.y + r3.w));
        return fmaf(ftanh(a16s), xd16, pgs);
    };

    // ---- time scan (uniform x scalars in SGPRs) ----
    const float* xb = x + (size_t)e * TT * FF;
    const bool hasc0 = (w != 0);
    const int  f0 = 2 * w - 1;
    const int  f1 = 2 * w;
    float xp0  = hasc0 ? uf(xb[f0]) : 0.0f;
    float xp1  = uf(xb[f1]);
    float xp16 = uf(xb[15]);
    float xn0  = hasc0 ? uf(xb[FF + f0]) : 0.0f;
    float xn1  = uf(xb[FF + f1]);
    float xn16 = uf(xb[FF + 15]);
    float dc0  = hasc0 ? (xn0 - xp0) : 1.0f;
    float dc1  = xn1 - xp1;
    float dc16 = xn16 - xp16;
    float dp0 = dc0, dp1 = dc1, dp16 = dc16;
    xp0 = xn0; xp1 = xn1; xp16 = xn16;

    #pragma unroll 1
    for (int t = 0; t < TT - 1; ++t) {
        const float f43 = 4.0f / 3.0f;
        float x20  = dp0  + f43 * (dc0  - dp0);
        float x21  = dp1  + f43 * (dc1  - dp1);
        float x216 = dp16 + f43 * (dc16 - dp16);

        int tn = (t + 2 < TT) ? (t + 2) : (TT - 1);
        float yn0  = hasc0 ? uf(xb[tn * FF + f0]) : 0.0f;
        float yn1  = uf(xb[tn * FF + f1]);
        float yn16 = uf(xb[tn * FF + 15]);

        float k1 = G(z, dp0, dp1, dp16);
        float k2 = G(z + k1 * (1.0f / 3.0f), dc0, dc1, dc16);
        float k3 = G(z + (k2 - k1 * (1.0f / 3.0f)), x20, x21, x216);
        float k4 = G(z + (k1 - k2 + k3), dc0, dc1, dc16);
        z = z + 0.125f * (k1 + 3.0f * (k2 + k3) + k4);

        if (w == 0) zT[((size_t)e * TT + t + 1) * HH + l] = z;

        dp0 = dc0; dp1 = dc1; dp16 = dc16;
        dc0 = hasc0 ? (yn0 - xp0) : 1.0f;
        dc1 = yn1 - xp1;
        dc16 = yn16 - xp16;
        xp0 = yn0; xp1 = yn1; xp16 = yn16;
    }
}

// out = gelu_exact(zT) @ w_proj + b_proj ; mask = 0
__global__ void ncde_proj(const float* __restrict__ zT,
                          const float* __restrict__ w_proj, const float* __restrict__ b_proj,
                          float* __restrict__ out, float* __restrict__ mask)
{
    __shared__ float gz[16][64];
    const int blk = blockIdx.x;
    const int tid = threadIdx.x;
    const int r16 = tid >> 4, f = tid & 15;
    const int row0 = blk * 16;

    #pragma unroll
    for (int i = 0; i < 4; ++i) {
        int idx = tid + i * 256;
        int r = idx >> 6, k = idx & 63;
        float zv = zT[(size_t)(row0 + r) * HH + k];
        gz[r][k] = 0.5f * zv * (1.0f + erff(zv * 0.70710678118654752f));
    }
    __syncthreads();

    float acc = b_proj[f];
    #pragma unroll
    for (int k = 0; k < 64; ++k)
        acc = fmaf(gz[r16][k], w_proj[k * FF + f], acc);
    out[(size_t)(row0 + r16) * FF + f] = acc;
    if (f == 0) mask[row0 + r16] = 0.0f;
}

extern "C" void kernel_launch(void* const* d_in, const int* in_sizes, int n_in,
                              void* d_out, int out_size, void* d_ws, size_t ws_size,
                              hipStream_t stream)
{
    (void)in_sizes; (void)n_in; (void)d_ws; (void)ws_size; (void)out_size;
    const float* x      = (const float*)d_in[0];
    const float* wi1    = (const float*)d_in[1];
    const float* bi1    = (const float*)d_in[2];
    const float* wi2    = (const float*)d_in[3];
    const float* bi2    = (const float*)d_in[4];
    const float* w_in   = (const float*)d_in[5];
    const float* b_in   = (const float*)d_in[6];
    const float* w_hid  = (const float*)d_in[7];
    const float* b_hid  = (const float*)d_in[8];
    const float* w_out  = (const float*)d_in[9];
    const float* b_out  = (const float*)d_in[10];
    const float* w_proj = (const float*)d_in[11];
    const float* b_proj = (const float*)d_in[12];

    float* zT   = (float*)d_out;                       // B*T*H
    float* outp = zT + (size_t)BB * TT * HH;           // B*T*F
    float* mask = outp + (size_t)BB * TT * FF;         // B*T

    ncde_main<<<dim3(BB / 2), dim3(1024), 0, stream>>>(
        x, wi1, bi1, wi2, bi2, w_in, b_in, w_hid, b_hid, w_out, b_out, zT);
    ncde_proj<<<dim3((BB * TT) / 16), dim3(256), 0, stream>>>(
        zT, w_proj, b_proj, outp, mask);
}

// Round 17
// 19143.529 us; speedup vs baseline: 1.1705x; 1.1705x over previous
//
#include <hip/hip_runtime.h>
#include <math.h>

#define BB 32
#define TT 2048
#define FF 16
#define CC 17
#define HH 64

typedef float v2f __attribute__((ext_vector_type(2)));
typedef float v4f __attribute__((ext_vector_type(4)));
typedef unsigned v4u __attribute__((ext_vector_type(4)));
typedef _Float16 h2 __attribute__((ext_vector_type(2)));

__device__ __forceinline__ float rl(float v, int lane) {
    return __int_as_float(__builtin_amdgcn_readlane(__float_as_int(v), lane));
}
__device__ __forceinline__ unsigned rlu(unsigned v, int lane) {
    return (unsigned)__builtin_amdgcn_readlane((int)v, lane);
}
__device__ __forceinline__ float uf(float v) {
    return __int_as_float(__builtin_amdgcn_readfirstlane(__float_as_int(v)));
}
__device__ __forceinline__ float ftanh(float x) {
    float e = __builtin_amdgcn_exp2f(x * 2.88539008177792681472f); // exp(2x)
    return 1.0f - 2.0f * __builtin_amdgcn_rcpf(e + 1.0f);
}
__device__ __forceinline__ float fdot2u(unsigned a, unsigned b, float c) {
    return __builtin_amdgcn_fdot2(__builtin_bit_cast(h2, a),
                                  __builtin_bit_cast(h2, b), c, false);
}
// pack (a,b) to f16x2, scaled by 2^8 (weights); RN; init-time only
__device__ __forceinline__ unsigned packw(float a, float b) {
    h2 p; p.x = (_Float16)(a * 256.0f); p.y = (_Float16)(b * 256.0f);
    return __builtin_bit_cast(unsigned, p);
}
// LDS-only barrier: no vmcnt(0) drain.
__device__ __forceinline__ void bar_lds() {
    asm volatile("s_waitcnt lgkmcnt(0)\n\ts_barrier" ::: "memory");
}
#define PIN(v) asm volatile("" : "+v"(v))

// R16 + bias fix: element B's c16 accumulator now also seeded with the folded
// bo16 (R16 seeded only element A -> absmax 72 failure; b_out[.,16] never
// reached B's tanh). Structure unchanged: dual batch element per block in the
// waves_per_eu(1,1) 256-VGPR regime (R7 evidence), 4 waves, wave w owns out
// cols 4w..4w+3 + hidden k-slice [16w,16w+16) + c16 k-slice; both elements in
// one instruction stream so independent dot2 chains fill LDS/barrier stalls.
__attribute__((amdgpu_waves_per_eu(1, 1)))
__launch_bounds__(256)
__global__ void ncde_main(const float* __restrict__ x,
                          const float* __restrict__ wi1, const float* __restrict__ bi1,
                          const float* __restrict__ wi2, const float* __restrict__ bi2,
                          const float* __restrict__ w_in, const float* __restrict__ b_in,
                          const float* __restrict__ w_hid, const float* __restrict__ b_hid,
                          const float* __restrict__ w_out, const float* __restrict__ b_out,
                          float* __restrict__ zT)
{
    const int bid = blockIdx.x;
    const int eA = 2 * bid, eB = 2 * bid + 1;
    const int tid = threadIdx.x;
    const int w   = tid >> 6;            // 0..3
    const int l   = tid & 63;

    __shared__ float pht[4][64][12];     // [layer][h-row][(A,B) x 4 wave-cols + pad]
    __shared__ float pgqt[64][20];       // [h-row][(pgA,a16A,pgB,a16B) x 4 cols + pad]
    __shared__ __align__(16) unsigned hbw[4][64];  // per-wave packed h pairs: A[0,32) B[32,64)

    const int cs = w ^ ((l >> 4) & 3);   // swizzled column (order-invariant sum)

    // ---- hidden weights: wave w owns k-slice [16w,16w+16), 8 u32/layer ----
    unsigned whp[4][8];
    #pragma unroll
    for (int jj = 0; jj < 8; ++jj) {
        int k = 16 * w + 2 * jj;
        whp[0][jj] = packw(w_in[k * HH + l],              w_in[(k + 1) * HH + l]);
        whp[1][jj] = packw(w_hid[(0 * HH + k) * HH + l],  w_hid[(0 * HH + k + 1) * HH + l]);
        whp[2][jj] = packw(w_hid[(1 * HH + k) * HH + l],  w_hid[(1 * HH + k + 1) * HH + l]);
        whp[3][jj] = packw(w_hid[(2 * HH + k) * HH + l],  w_hid[(2 * HH + k + 1) * HH + l]);
    }
    float bfold[4];
    bfold[0] = (w == 0) ? b_in[l] : 0.0f;
    bfold[1] = (w == 0) ? b_hid[0 * HH + l] : 0.0f;
    bfold[2] = (w == 0) ? b_hid[1 * HH + l] : 0.0f;
    bfold[3] = (w == 0) ? b_hid[2 * HH + l] : 0.0f;

    // ---- out-layer: 4 columns per wave + c16 k-slice ----
    unsigned wop0[32], wop1[32], wop2[32], wop3[32], w16p[8];
    #pragma unroll
    for (int j = 0; j < 32; ++j) {
        wop0[j] = packw(w_out[(2 * j) * (CC * HH) + l * CC + 4 * w + 0],
                        w_out[(2 * j + 1) * (CC * HH) + l * CC + 4 * w + 0]);
        wop1[j] = packw(w_out[(2 * j) * (CC * HH) + l * CC + 4 * w + 1],
                        w_out[(2 * j + 1) * (CC * HH) + l * CC + 4 * w + 1]);
        wop2[j] = packw(w_out[(2 * j) * (CC * HH) + l * CC + 4 * w + 2],
                        w_out[(2 * j + 1) * (CC * HH) + l * CC + 4 * w + 2]);
        wop3[j] = packw(w_out[(2 * j) * (CC * HH) + l * CC + 4 * w + 3],
                        w_out[(2 * j + 1) * (CC * HH) + l * CC + 4 * w + 3]);
    }
    #pragma unroll
    for (int jj = 0; jj < 8; ++jj)
        w16p[jj] = packw(w_out[(16 * w + 2 * jj) * (CC * HH) + l * CC + 16],
                         w_out[(16 * w + 2 * jj + 1) * (CC * HH) + l * CC + 16]);
    float bo0 = b_out[l * CC + 4 * w + 0];
    float bo1 = b_out[l * CC + 4 * w + 1];
    float bo2 = b_out[l * CC + 4 * w + 2];
    float bo3 = b_out[l * CC + 4 * w + 3];
    float bo16 = (w == 0) ? b_out[l * CC + 16] : 0.0f;   // folded into wave0 a16 partials

    #pragma unroll
    for (int j = 0; j < 32; ++j) { PIN(wop0[j]); PIN(wop1[j]); PIN(wop2[j]); PIN(wop3[j]); }
    #pragma unroll
    for (int jj = 0; jj < 8; ++jj) { PIN(w16p[jj]); }
    #pragma unroll
    for (int lay = 0; lay < 4; ++lay) {
        #pragma unroll
        for (int jj = 0; jj < 8; ++jj) PIN(whp[lay][jj]);
    }
    PIN(bo0); PIN(bo1); PIN(bo2); PIN(bo3); PIN(bo16);

    // ---- z0 for both elements ----
    float zA, zB;
    {
        float h0A = bi1[l], h0B = h0A;
        #pragma unroll
        for (int c = 1; c < CC; ++c) {
            float w1 = wi1[c * HH + l];
            h0A = fmaf(x[(size_t)eA * TT * FF + (c - 1)], w1, h0A);
            h0B = fmaf(x[(size_t)eB * TT * FF + (c - 1)], w1, h0B);
        }
        h0A = fmaxf(h0A, 0.0f); h0B = fmaxf(h0B, 0.0f);
        zA = bi2[l]; zB = zA;
        #pragma unroll
        for (int k = 0; k < 64; ++k) {
            float w2 = wi2[k * HH + l];
            zA = fmaf(rl(h0A, k), w2, zA);
            zB = fmaf(rl(h0B, k), w2, zB);
        }
    }
    if (w == 0) zT[(size_t)eA * TT * HH + l] = zA;
    if (w == 1) zT[(size_t)eB * TT * HH + l] = zB;

    // pack v*2^-8 into f16x2; pair p=(v[2p],v[2p+1]) lives in lanes 2p,2p+1
    auto packb = [&](float v) -> unsigned {
        float hs = v * 0.00390625f;
        float pr = __shfl_xor(hs, 1);
        float a  = (l & 1) ? pr : hs;
        float bb = (l & 1) ? hs : pr;
        return __builtin_bit_cast(unsigned, __builtin_amdgcn_cvt_pkrtz(a, bb));
    };

    // ---- fused dual g() ----
    auto G2 = [&](float ziA, float ziB,
                  float xa0, float xa1, float xa2, float xa3, float xa16,
                  float xb0, float xb1, float xb2, float xb3, float xb16) -> v2f {
        float cA = ziA, cB = ziB;
        #pragma unroll
        for (int L = 0; L < 4; ++L) {
            unsigned hpA = packb(cA), hpB = packb(cB);
            float aA0 = bfold[L], aA1 = 0.0f, aB0 = bfold[L], aB1 = 0.0f;
            #pragma unroll
            for (int jj = 0; jj < 8; jj += 2) {
                unsigned sA0 = rlu(hpA, 16 * w + 2 * jj);
                unsigned sA1 = rlu(hpA, 16 * w + 2 * jj + 2);
                unsigned sB0 = rlu(hpB, 16 * w + 2 * jj);
                unsigned sB1 = rlu(hpB, 16 * w + 2 * jj + 2);
                aA0 = fdot2u(sA0, whp[L][jj],     aA0);
                aA1 = fdot2u(sA1, whp[L][jj + 1], aA1);
                aB0 = fdot2u(sB0, whp[L][jj],     aB0);
                aB1 = fdot2u(sB1, whp[L][jj + 1], aB1);
            }
            *reinterpret_cast<v2f*>(&pht[L][l][2 * cs]) = (v2f){ aA0 + aA1, aB0 + aB1 };
            bar_lds();
            const float* row = &pht[L][l][0];
            v4f q0 = *reinterpret_cast<const v4f*>(row);      // (A,B) cols x2
            v4f q1 = *reinterpret_cast<const v4f*>(row + 4);  // (A,B) cols x2
            cA = fmaxf((q0.x + q0.z) + (q1.x + q1.z), 0.0f);
            cB = fmaxf((q0.y + q0.w) + (q1.y + q1.w), 0.0f);
        }
        // out layer: private per-wave LDS h broadcast (no readlanes, no barrier)
        unsigned hpA = packb(cA), hpB = packb(cB);
        if ((l & 1) == 0) { hbw[w][l >> 1] = hpA; hbw[w][32 + (l >> 1)] = hpB; }
        float uA0 = 0.f, uA1 = 0.f, uA2 = 0.f, uA3 = 0.f;
        float uB0 = 0.f, uB1 = 0.f, uB2 = 0.f, uB3 = 0.f;
        #pragma unroll
        for (int j = 0; j < 8; ++j) {
            v4u qA = *reinterpret_cast<const v4u*>(&hbw[w][4 * j]);
            v4u qB = *reinterpret_cast<const v4u*>(&hbw[w][32 + 4 * j]);
            uA0 = fdot2u(qA.x, wop0[4 * j + 0], uA0);
            uA0 = fdot2u(qA.y, wop0[4 * j + 1], uA0);
            uA0 = fdot2u(qA.z, wop0[4 * j + 2], uA0);
            uA0 = fdot2u(qA.w, wop0[4 * j + 3], uA0);
            uA1 = fdot2u(qA.x, wop1[4 * j + 0], uA1);
            uA1 = fdot2u(qA.y, wop1[4 * j + 1], uA1);
            uA1 = fdot2u(qA.z, wop1[4 * j + 2], uA1);
            uA1 = fdot2u(qA.w, wop1[4 * j + 3], uA1);
            uA2 = fdot2u(qA.x, wop2[4 * j + 0], uA2);
            uA2 = fdot2u(qA.y, wop2[4 * j + 1], uA2);
            uA2 = fdot2u(qA.z, wop2[4 * j + 2], uA2);
            uA2 = fdot2u(qA.w, wop2[4 * j + 3], uA2);
            uA3 = fdot2u(qA.x, wop3[4 * j + 0], uA3);
            uA3 = fdot2u(qA.y, wop3[4 * j + 1], uA3);
            uA3 = fdot2u(qA.z, wop3[4 * j + 2], uA3);
            uA3 = fdot2u(qA.w, wop3[4 * j + 3], uA3);
            uB0 = fdot2u(qB.x, wop0[4 * j + 0], uB0);
            uB0 = fdot2u(qB.y, wop0[4 * j + 1], uB0);
            uB0 = fdot2u(qB.z, wop0[4 * j + 2], uB0);
            uB0 = fdot2u(qB.w, wop0[4 * j + 3], uB0);
            uB1 = fdot2u(qB.x, wop1[4 * j + 0], uB1);
            uB1 = fdot2u(qB.y, wop1[4 * j + 1], uB1);
            uB1 = fdot2u(qB.z, wop1[4 * j + 2], uB1);
            uB1 = fdot2u(qB.w, wop1[4 * j + 3], uB1);
            uB2 = fdot2u(qB.x, wop2[4 * j + 0], uB2);
            uB2 = fdot2u(qB.y, wop2[4 * j + 1], uB2);
            uB2 = fdot2u(qB.z, wop2[4 * j + 2], uB2);
            uB2 = fdot2u(qB.w, wop2[4 * j + 3], uB2);
            uB3 = fdot2u(qB.x, wop3[4 * j + 0], uB3);
            uB3 = fdot2u(qB.y, wop3[4 * j + 1], uB3);
            uB3 = fdot2u(qB.z, wop3[4 * j + 2], uB3);
            uB3 = fdot2u(qB.w, wop3[4 * j + 3], uB3);
        }
        // c16 k-slice: pairs 8w..8w+7 (bias folded into BOTH elements' wave0 partials)
        v4u qcA0 = *reinterpret_cast<const v4u*>(&hbw[w][8 * w]);
        v4u qcA1 = *reinterpret_cast<const v4u*>(&hbw[w][8 * w + 4]);
        v4u qcB0 = *reinterpret_cast<const v4u*>(&hbw[w][32 + 8 * w]);
        v4u qcB1 = *reinterpret_cast<const v4u*>(&hbw[w][32 + 8 * w + 4]);
        float a16A = bo16, a16B = bo16;   // <- R16 bug: a16B was 0 (B lost its bias)
        a16A = fdot2u(qcA0.x, w16p[0], a16A); a16A = fdot2u(qcA0.y, w16p[1], a16A);
        a16A = fdot2u(qcA0.z, w16p[2], a16A); a16A = fdot2u(qcA0.w, w16p[3], a16A);
        a16A = fdot2u(qcA1.x, w16p[4], a16A); a16A = fdot2u(qcA1.y, w16p[5], a16A);
        a16A = fdot2u(qcA1.z, w16p[6], a16A); a16A = fdot2u(qcA1.w, w16p[7], a16A);
        a16B = fdot2u(qcB0.x, w16p[0], a16B); a16B = fdot2u(qcB0.y, w16p[1], a16B);
        a16B = fdot2u(qcB0.z, w16p[2], a16B); a16B = fdot2u(qcB0.w, w16p[3], a16B);
        a16B = fdot2u(qcB1.x, w16p[4], a16B); a16B = fdot2u(qcB1.y, w16p[5], a16B);
        a16B = fdot2u(qcB1.z, w16p[6], a16B); a16B = fdot2u(qcB1.w, w16p[7], a16B);

        float pgA = ftanh(uA0 + bo0) * xa0 + ftanh(uA1 + bo1) * xa1
                  + ftanh(uA2 + bo2) * xa2 + ftanh(uA3 + bo3) * xa3;
        float pgB = ftanh(uB0 + bo0) * xb0 + ftanh(uB1 + bo1) * xb1
                  + ftanh(uB2 + bo2) * xb2 + ftanh(uB3 + bo3) * xb3;
        *reinterpret_cast<v4f*>(&pgqt[l][4 * cs]) = (v4f){ pgA, a16A, pgB, a16B };
        bar_lds();
        const float* prow = &pgqt[l][0];
        v4f r0 = *reinterpret_cast<const v4f*>(prow);
        v4f r1 = *reinterpret_cast<const v4f*>(prow + 4);
        v4f r2 = *reinterpret_cast<const v4f*>(prow + 8);
        v4f r3 = *reinterpret_cast<const v4f*>(prow + 12);
        float pgAs  = (r0.x + r1.x) + (r2.x + r3.x);
        float a16As = (r0.y + r1.y) + (r2.y + r3.y);
        float pgBs  = (r0.z + r1.z) + (r2.z + r3.z);
        float a16Bs = (r0.w + r1.w) + (r2.w + r3.w);
        return (v2f){ fmaf(ftanh(a16As), xa16, pgAs),
                      fmaf(ftanh(a16Bs), xb16, pgBs) };
    };

    // ---- time scan: wave w carries channels 4w..4w+3 (+ shared ch16) ----
    const float* xA = x + (size_t)eA * TT * FF;
    const float* xB = x + (size_t)eB * TT * FF;
    const int fb = 4 * w - 1;            // feature of col 4w (fb<0 => time channel)

    float xpA[4], dcA[4], dpA[4], xpB[4], dcB[4], dpB[4];
    float xpA16, dcA16, dpA16, xpB16, dcB16, dpB16;
    #pragma unroll
    for (int i = 0; i < 4; ++i) {
        int f = fb + i;
        float a0 = (f < 0) ? 0.f : uf(xA[f]);
        float a1 = (f < 0) ? 0.f : uf(xA[FF + f]);
        float b0 = (f < 0) ? 0.f : uf(xB[f]);
        float b1 = (f < 0) ? 0.f : uf(xB[FF + f]);
        dcA[i] = (f < 0) ? 1.0f : (a1 - a0);  dpA[i] = dcA[i];  xpA[i] = a1;
        dcB[i] = (f < 0) ? 1.0f : (b1 - b0);  dpB[i] = dcB[i];  xpB[i] = b1;
    }
    { float a0 = uf(xA[15]), a1 = uf(xA[FF + 15]);
      dcA16 = a1 - a0; dpA16 = dcA16; xpA16 = a1;
      float b0 = uf(xB[15]), b1 = uf(xB[FF + 15]);
      dcB16 = b1 - b0; dpB16 = dcB16; xpB16 = b1; }

    #pragma unroll 1
    for (int t = 0; t < TT - 1; ++t) {
        const float f43 = 4.0f / 3.0f;
        float x2A[4], x2B[4];
        #pragma unroll
        for (int i = 0; i < 4; ++i) {
            x2A[i] = dpA[i] + f43 * (dcA[i] - dpA[i]);
            x2B[i] = dpB[i] + f43 * (dcB[i] - dpB[i]);
        }
        float x2A16 = dpA16 + f43 * (dcA16 - dpA16);
        float x2B16 = dpB16 + f43 * (dcB16 - dpB16);

        int tn = (t + 2 < TT) ? (t + 2) : (TT - 1);
        float ynA[4], ynB[4];
        #pragma unroll
        for (int i = 0; i < 4; ++i) {
            int f = fb + i;
            ynA[i] = (f < 0) ? 0.f : uf(xA[tn * FF + f]);
            ynB[i] = (f < 0) ? 0.f : uf(xB[tn * FF + f]);
        }
        float ynA16 = uf(xA[tn * FF + 15]);
        float ynB16 = uf(xB[tn * FF + 15]);

        v2f k1 = G2(zA, zB,
                    dpA[0], dpA[1], dpA[2], dpA[3], dpA16,
                    dpB[0], dpB[1], dpB[2], dpB[3], dpB16);
        v2f k2 = G2(zA + k1.x * (1.0f / 3.0f), zB + k1.y * (1.0f / 3.0f),
                    dcA[0], dcA[1], dcA[2], dcA[3], dcA16,
                    dcB[0], dcB[1], dcB[2], dcB[3], dcB16);
        v2f k3 = G2(zA + (k2.x - k1.x * (1.0f / 3.0f)), zB + (k2.y - k1.y * (1.0f / 3.0f)),
                    x2A[0], x2A[1], x2A[2], x2A[3], x2A16,
                    x2B[0], x2B[1], x2B[2], x2B[3], x2B16);
        v2f k4 = G2(zA + (k1.x - k2.x + k3.x), zB + (k1.y - k2.y + k3.y),
                    dcA[0], dcA[1], dcA[2], dcA[3], dcA16,
                    dcB[0], dcB[1], dcB[2], dcB[3], dcB16);
        zA += 0.125f * (k1.x + 3.0f * (k2.x + k3.x) + k4.x);
        zB += 0.125f * (k1.y + 3.0f * (k2.y + k3.y) + k4.y);

        if (w == 0) zT[((size_t)eA * TT + t + 1) * HH + l] = zA;
        if (w == 1) zT[((size_t)eB * TT + t + 1) * HH + l] = zB;

        #pragma unroll
        for (int i = 0; i < 4; ++i) {
            dpA[i] = dcA[i]; dpB[i] = dcB[i];
            dcA[i] = (fb + i < 0) ? 1.0f : (ynA[i] - xpA[i]);
            dcB[i] = (fb + i < 0) ? 1.0f : (ynB[i] - xpB[i]);
            xpA[i] = ynA[i]; xpB[i] = ynB[i];
        }
        dpA16 = dcA16; dcA16 = ynA16 - xpA16; xpA16 = ynA16;
        dpB16 = dcB16; dcB16 = ynB16 - xpB16; xpB16 = ynB16;
    }
}

// out = gelu_exact(zT) @ w_proj + b_proj ; mask = 0
__global__ void ncde_proj(const float* __restrict__ zT,
                          const float* __restrict__ w_proj, const float* __restrict__ b_proj,
                          float* __restrict__ out, float* __restrict__ mask)
{
    __shared__ float gz[16][64];
    const int blk = blockIdx.x;
    const int tid = threadIdx.x;
    const int r16 = tid >> 4, f = tid & 15;
    const int row0 = blk * 16;

    #pragma unroll
    for (int i = 0; i < 4; ++i) {
        int idx = tid + i * 256;
        int r = idx >> 6, k = idx & 63;
        float zv = zT[(size_t)(row0 + r) * HH + k];
        gz[r][k] = 0.5f * zv * (1.0f + erff(zv * 0.70710678118654752f));
    }
    __syncthreads();

    float acc = b_proj[f];
    #pragma unroll
    for (int k = 0; k < 64; ++k)
        acc = fmaf(gz[r16][k], w_proj[k * FF + f], acc);
    out[(size_t)(row0 + r16) * FF + f] = acc;
    if (f == 0) mask[row0 + r16] = 0.0f;
}

extern "C" void kernel_launch(void* const* d_in, const int* in_sizes, int n_in,
                              void* d_out, int out_size, void* d_ws, size_t ws_size,
                              hipStream_t stream)
{
    (void)in_sizes; (void)n_in; (void)d_ws; (void)ws_size; (void)out_size;
    const float* x      = (const float*)d_in[0];
    const float* wi1    = (const float*)d_in[1];
    const float* bi1    = (const float*)d_in[2];
    const float* wi2    = (const float*)d_in[3];
    const float* bi2    = (const float*)d_in[4];
    const float* w_in   = (const float*)d_in[5];
    const float* b_in   = (const float*)d_in[6];
    const float* w_hid  = (const float*)d_in[7];
    const float* b_hid  = (const float*)d_in[8];
    const float* w_out  = (const float*)d_in[9];
    const float* b_out  = (const float*)d_in[10];
    const float* w_proj = (const float*)d_in[11];
    const float* b_proj = (const float*)d_in[12];

    float* zT   = (float*)d_out;                       // B*T*H
    float* outp = zT + (size_t)BB * TT * HH;           // B*T*F
    float* mask = outp + (size_t)BB * TT * FF;         // B*T

    ncde_main<<<dim3(BB / 2), dim3(256), 0, stream>>>(
        x, wi1, bi1, wi2, bi2, w_in, b_in, w_hid, b_hid, w_out, b_out, zT);
    ncde_proj<<<dim3((BB * TT) / 16), dim3(256), 0, stream>>>(
        zT, w_proj, b_proj, outp, mask);
}